// Round 1
// baseline (270.406 us; speedup 1.0000x reference)
//
#include <hip/hip_runtime.h>
#include <math.h>

// Router: logits = x @ w^T, top-2 + softmax, stable k-major position-in-expert,
// capacity masking. N tokens (multiple of 64), C=1024, E=64, k=2.
//
// Kernel 1: tiled fp32 GEMM (64 tokens x 64 experts per block) + per-token
//           top-2/softmax + per-group expert histograms.
// Kernel 2: per-group exclusive prefix over histograms (streamed from L2) +
//           wave-level stable intra-group ordering via ballot match-any +
//           all output writes.

#define C_DIM 1024

__global__ __launch_bounds__(256) void router_gemm_top2(
    const float* __restrict__ x, const float* __restrict__ w,
    int2* __restrict__ idx_ws, float2* __restrict__ probs_ws,
    int* __restrict__ hist)
{
    __shared__ float xs[64][36];   // stride 36: float4-aligned, 2-way-bank (free)
    __shared__ float wsh[64][36];
    __shared__ float lg[64][65];   // +1 pad for the top-2 row scan
    __shared__ int   h2[128];      // [k][expert] histogram for this group

    const int b   = blockIdx.x;
    const int tid = threadIdx.x;
    const int n0  = b * 64;

    const int lr = tid >> 3;          // 0..31 staging row
    const int lc = (tid & 7) * 4;     // staging col (float4)
    const int tm = tid >> 4;          // 0..15 token group
    const int te = tid & 15;          // 0..15 expert group

    float acc[4][4];
    #pragma unroll
    for (int i = 0; i < 4; ++i)
        #pragma unroll
        for (int j = 0; j < 4; ++j) acc[i][j] = 0.f;

    for (int ck = 0; ck < C_DIM; ck += 32) {
        float4 xv0 = *(const float4*)(x + (size_t)(n0 + lr)      * C_DIM + ck + lc);
        float4 xv1 = *(const float4*)(x + (size_t)(n0 + lr + 32) * C_DIM + ck + lc);
        float4 wv0 = *(const float4*)(w + (size_t)lr        * C_DIM + ck + lc);
        float4 wv1 = *(const float4*)(w + (size_t)(lr + 32) * C_DIM + ck + lc);
        __syncthreads();   // WAR: previous iter's compute reads xs/wsh
        *(float4*)&xs[lr][lc]       = xv0;
        *(float4*)&xs[lr + 32][lc]  = xv1;
        *(float4*)&wsh[lr][lc]      = wv0;
        *(float4*)&wsh[lr + 32][lc] = wv1;
        __syncthreads();
        #pragma unroll
        for (int k4 = 0; k4 < 8; ++k4) {
            float4 a[4], bb[4];
            a[0]  = *(float4*)&xs[tm][k4 * 4];
            a[1]  = *(float4*)&xs[tm + 16][k4 * 4];
            a[2]  = *(float4*)&xs[tm + 32][k4 * 4];
            a[3]  = *(float4*)&xs[tm + 48][k4 * 4];
            bb[0] = *(float4*)&wsh[te][k4 * 4];
            bb[1] = *(float4*)&wsh[te + 16][k4 * 4];
            bb[2] = *(float4*)&wsh[te + 32][k4 * 4];
            bb[3] = *(float4*)&wsh[te + 48][k4 * 4];
            #pragma unroll
            for (int i = 0; i < 4; ++i)
                #pragma unroll
                for (int j = 0; j < 4; ++j)
                    acc[i][j] += a[i].x * bb[j].x + a[i].y * bb[j].y +
                                 a[i].z * bb[j].z + a[i].w * bb[j].w;
        }
    }

    // scatter logits into LDS (token-major rows, padded stride)
    #pragma unroll
    for (int i = 0; i < 4; ++i)
        #pragma unroll
        for (int j = 0; j < 4; ++j)
            lg[tm + 16 * i][te + 16 * j] = acc[i][j];
    if (tid < 128) h2[tid] = 0;
    __syncthreads();

    if (tid < 64) {
        const int n = n0 + tid;
        float m1 = -3.0e38f, m2 = -3.0e38f;
        int   i1 = 0, i2 = 0;
        for (int e = 0; e < 64; ++e) {
            float v = lg[tid][e];
            if (v > m1)      { m2 = m1; i2 = i1; m1 = v; i1 = e; }
            else if (v > m2) { m2 = v;  i2 = e; }
        }
        float e2 = expf(m2 - m1);           // <= 1
        float s  = 1.f / (1.f + e2);
        probs_ws[n] = make_float2(s, e2 * s);
        idx_ws[n]   = make_int2(i1, i2);
        atomicAdd(&h2[i1], 1);
        atomicAdd(&h2[64 + i2], 1);
    }
    __syncthreads();
    if (tid < 128) hist[b * 128 + tid] = h2[tid];
}

__global__ __launch_bounds__(64) void router_rank_out(
    const int2* __restrict__ idx_ws, const float2* __restrict__ probs_ws,
    const int* __restrict__ hist,
    float* __restrict__ out_mask, float* __restrict__ out_probs,
    float* __restrict__ out_idx,  float* __restrict__ out_rank,
    int G, int cap)
{
    __shared__ int offT[128];   // exclusive offsets per (k,expert) for this group
    __shared__ int totT[64];    // total k=0 count per expert

    const int g = blockIdx.x;
    const int l = threadIdx.x;  // one wave

    // lane l owns pairs (2l, 2l+1); l<32 -> k=0 experts, l>=32 -> k=1 experts
    const int2* h2 = (const int2*)hist;   // [G][64] int2 rows
    int offE = 0, offO = 0, totE = 0, totO = 0;
    #pragma unroll 4
    for (int gp = 0; gp < g; ++gp) { int2 v = h2[(size_t)gp * 64 + l]; offE += v.x; offO += v.y; }
    #pragma unroll 4
    for (int gp = g; gp < G; ++gp) { int2 v = h2[(size_t)gp * 64 + l]; totE += v.x; totO += v.y; }

    offT[2 * l]     = offE;
    offT[2 * l + 1] = offO;
    if (l < 32) {
        totT[2 * l]     = offE + totE;
        totT[2 * l + 1] = offO + totO;
    }
    __syncthreads();
    if (l >= 32) {   // k=1 offsets get full k=0 totals added (k-major cumsum)
        offT[2 * l]     += totT[2 * l - 64];
        offT[2 * l + 1] += totT[2 * l - 63];
    }
    __syncthreads();

    const int n = g * 64 + l;
    int2   ii = idx_ws[n];
    float2 pp = probs_ws[n];

    // wave match-any: mask of lanes with the same expert, per k-slot
    unsigned long long below = (l == 63) ? 0x7FFFFFFFFFFFFFFFull
                                         : ((1ull << l) - 1ull);
    unsigned long long m0 = ~0ull, m1 = ~0ull;
    #pragma unroll
    for (int bi = 0; bi < 6; ++bi) {
        unsigned long long b0 = __ballot((ii.x >> bi) & 1);
        unsigned long long b1 = __ballot((ii.y >> bi) & 1);
        m0 &= ((ii.x >> bi) & 1) ? b0 : ~b0;
        m1 &= ((ii.y >> bi) & 1) ? b1 : ~b1;
    }
    int rank0 = offT[ii.x]      + __popcll(m0 & below);
    int rank1 = offT[64 + ii.y] + __popcll(m1 & below);
    int c0 = rank0 < cap;
    int c1 = rank1 < cap;

    float* mrow = out_mask + (size_t)n * 128;
    float4 z = make_float4(0.f, 0.f, 0.f, 0.f);
    #pragma unroll
    for (int t = 0; t < 32; ++t) *(float4*)(mrow + 4 * t) = z;
    if (c0) mrow[ii.x]      = 1.f;
    if (c1) mrow[64 + ii.y] = 1.f;

    out_probs[2 * n]     = c0 ? pp.x : 0.f;
    out_probs[2 * n + 1] = c1 ? pp.y : 0.f;
    out_idx[2 * n]       = (float)ii.x;
    out_idx[2 * n + 1]   = (float)ii.y;
    out_rank[2 * n]      = (float)rank0;
    out_rank[2 * n + 1]  = (float)rank1;
}

extern "C" void kernel_launch(void* const* d_in, const int* in_sizes, int n_in,
                              void* d_out, int out_size, void* d_ws, size_t ws_size,
                              hipStream_t stream) {
    const float* x = (const float*)d_in[0];
    const float* w = (const float*)d_in[1];
    const int N = in_sizes[0] / C_DIM;    // 32768
    const int G = N / 64;                 // 512

    // eval-mode capacity: floor(2 * 2.0 * N / 64), round up to even, min 4
    int cap = (int)floor(2.0 * 2.0 * (double)N / 64.0);
    cap += cap & 1;
    if (cap < 4) cap = 4;

    int2*   idx_ws   = (int2*)d_ws;
    float2* probs_ws = (float2*)((char*)d_ws + (size_t)N * 8);
    int*    hist     = (int*)((char*)d_ws + (size_t)N * 16);

    float* out       = (float*)d_out;
    float* out_mask  = out;                          // N*2*64
    float* out_probs = out + (size_t)N * 128;        // N*2
    float* out_idx   = out_probs + (size_t)N * 2;    // N*2
    float* out_rank  = out_idx + (size_t)N * 2;      // N*2

    hipLaunchKernelGGL(router_gemm_top2, dim3(G), dim3(256), 0, stream,
                       x, w, idx_ws, probs_ws, hist);
    hipLaunchKernelGGL(router_rank_out, dim3(G), dim3(64), 0, stream,
                       idx_ws, probs_ws, hist, out_mask, out_probs, out_idx,
                       out_rank, G, cap);
}

// Round 2
// 264.996 us; speedup vs baseline: 1.0204x; 1.0204x over previous
//
#include <hip/hip_runtime.h>
#include <math.h>

// Router: logits = x @ w^T (N=32768 tokens, C=1024, E=64), top-2 + softmax,
// stable k-major position-in-expert, capacity mask.
//
// K1: transpose w -> w_t[k][e] so per-k expert rows are contiguous (SGPR-loadable)
// K2: main GEMM: 64 tokens/block, 8 K-slices (one per wave). Each thread owns one
//     token with acc[64]; B-operand comes from SGPRs (wave-uniform s_load), A from
//     LDS (1 ds_read_b128 per 256 FMAs). Cross-wave LDS reduce, top-2, histogram.
// K3: column-wise exclusive scan of group histograms (replaces O(G^2) loop)
// K4: rank via ballot match-any + all outputs (mask staged in LDS, coalesced)

#define C_DIM 1024
#define CK 256

__global__ __launch_bounds__(256) void wt_kernel(const float* __restrict__ w,
                                                 float* __restrict__ w_t) {
    int i = blockIdx.x * 256 + threadIdx.x;   // 65536 elements
    int e = i >> 10, k = i & 1023;
    w_t[k * 64 + e] = w[i];
}

__global__ __launch_bounds__(512, 4) void router_main(
    const float* __restrict__ x, const float* __restrict__ w_t,
    int2* __restrict__ idx_ws, float2* __restrict__ probs_ws,
    int* __restrict__ hist)
{
    __shared__ __align__(16) float smem[64 * 260];   // xs[64][260]; later aliased
    // aliased region (used only after the post-compute barrier):
    //   lg  = smem as [64][68] logits
    //   h2  = 128 ints at smem + 64*68
    int* h2 = (int*)(smem + 64 * 68);

    const int b   = blockIdx.x;
    const int tid = threadIdx.x;
    const int n0  = b * 64;
    const int l   = tid & 63;                                   // token in block
    const int s   = __builtin_amdgcn_readfirstlane(tid >> 6);   // K-slice = wave id

    float acc[64];
    #pragma unroll
    for (int e = 0; e < 64; ++e) acc[e] = 0.f;

    for (int ck = 0; ck < C_DIM; ck += CK) {
        __syncthreads();   // WAR on xs
        {   // stage 64 rows x 256 floats, coalesced
            int r  = tid >> 3;
            int c4 = tid & 7;
            #pragma unroll
            for (int j = 0; j < 8; ++j) {
                int c = (c4 + 8 * j) * 4;
                *(float4*)&smem[r * 260 + c] =
                    *(const float4*)(x + (size_t)(n0 + r) * C_DIM + ck + c);
            }
        }
        __syncthreads();
        const float* wt = w_t + (size_t)(ck + s * 32) * 64;   // wave-uniform
        for (int kk4 = 0; kk4 < 8; ++kk4) {
            float4 xv = *(const float4*)&smem[l * 260 + s * 32 + kk4 * 4];
            const float* wk = wt + kk4 * 256;
            #pragma unroll
            for (int q = 0; q < 4; ++q) {
                float xc = (q == 0) ? xv.x : (q == 1) ? xv.y : (q == 2) ? xv.z : xv.w;
                const float* wq = wk + q * 64;   // wave-uniform -> s_load
                #pragma unroll
                for (int e = 0; e < 64; ++e)
                    acc[e] = fmaf(xc, wq[e], acc[e]);
            }
        }
    }
    __syncthreads();   // all xs reads done; safe to alias smem

    if (tid < 128) h2[tid] = 0;
    // serial per-wave reduction of the 8 K-slices into lg[token][expert]
    for (int r = 0; r < 8; ++r) {
        if (s == r) {
            if (r == 0) {
                #pragma unroll
                for (int e = 0; e < 64; ++e) smem[l * 68 + e] = acc[e];
            } else {
                #pragma unroll
                for (int e = 0; e < 64; ++e) smem[l * 68 + e] += acc[e];
            }
        }
        __syncthreads();
    }

    if (tid < 64) {
        float m1 = -3.0e38f, m2 = -3.0e38f;
        int   i1 = 0, i2 = 0;
        for (int e = 0; e < 64; ++e) {
            float v = smem[tid * 68 + e];
            if (v > m1)      { m2 = m1; i2 = i1; m1 = v; i1 = e; }
            else if (v > m2) { m2 = v;  i2 = e; }
        }
        float e2 = expf(m2 - m1);            // <= 1
        float p1 = 1.f / (1.f + e2);
        int n = n0 + tid;
        probs_ws[n] = make_float2(p1, e2 * p1);
        idx_ws[n]   = make_int2(i1, i2);
        atomicAdd(&h2[i1], 1);
        atomicAdd(&h2[64 + i2], 1);
    }
    __syncthreads();
    if (tid < 128) hist[b * 128 + tid] = h2[tid];
}

// exclusive prefix over groups for each of the 128 (k,expert) columns
__global__ __launch_bounds__(256) void scan_kernel(const int* __restrict__ hist,
                                                   int* __restrict__ offs,
                                                   int* __restrict__ tot, int G) {
    int c = blockIdx.x;          // 0..127
    int t = threadIdx.x;
    int ipt = G / 256;           // 2 for G=512
    int base = t * ipt;
    int sum = 0;
    for (int j = 0; j < ipt; ++j) sum += hist[(size_t)(base + j) * 128 + c];
    int lane = t & 63, wv = t >> 6;
    int sc = sum;
    #pragma unroll
    for (int d = 1; d < 64; d <<= 1) {
        int o = __shfl_up(sc, d, 64);
        if (lane >= d) sc += o;
    }
    __shared__ int wtot[4];
    if (lane == 63) wtot[wv] = sc;
    __syncthreads();
    int pre = 0;
    for (int w2 = 0; w2 < wv; ++w2) pre += wtot[w2];
    int run = pre + sc - sum;    // exclusive prefix for this thread's items
    for (int j = 0; j < ipt; ++j) {
        int v = hist[(size_t)(base + j) * 128 + c];
        offs[(size_t)(base + j) * 128 + c] = run;
        run += v;
    }
    if (t == 255) tot[c] = run;  // column total
}

__global__ __launch_bounds__(64) void rank_out(
    const int2* __restrict__ idx_ws, const float2* __restrict__ probs_ws,
    const int* __restrict__ offs, const int* __restrict__ tot,
    float* __restrict__ out_mask, float* __restrict__ out_probs,
    float* __restrict__ out_idx,  float* __restrict__ out_rank, int cap)
{
    __shared__ float msk[64 * 128];   // 32 KB
    const int g = blockIdx.x, l = threadIdx.x;
    const int n = g * 64 + l;

    #pragma unroll
    for (int j = 0; j < 32; ++j)
        *(float4*)&msk[(j * 64 + l) * 4] = make_float4(0.f, 0.f, 0.f, 0.f);

    int2   ii = idx_ws[n];
    float2 pp = probs_ws[n];
    int off0 = offs[g * 128 + ii.x];
    int off1 = offs[g * 128 + 64 + ii.y] + tot[ii.y];   // k-major fixup

    unsigned long long below = (1ull << l) - 1ull;
    unsigned long long m0 = ~0ull, m1 = ~0ull;
    #pragma unroll
    for (int bi = 0; bi < 6; ++bi) {
        unsigned long long b0 = __ballot((ii.x >> bi) & 1);
        unsigned long long b1 = __ballot((ii.y >> bi) & 1);
        m0 &= ((ii.x >> bi) & 1) ? b0 : ~b0;
        m1 &= ((ii.y >> bi) & 1) ? b1 : ~b1;
    }
    int rank0 = off0 + __popcll(m0 & below);
    int rank1 = off1 + __popcll(m1 & below);
    int c0 = rank0 < cap;
    int c1 = rank1 < cap;

    __syncthreads();
    if (c0) msk[l * 128 + ii.x] = 1.f;
    if (c1) msk[l * 128 + 64 + ii.y] = 1.f;
    __syncthreads();

    float* mrow = out_mask + (size_t)g * 8192;
    #pragma unroll
    for (int j = 0; j < 32; ++j) {
        int idx = (j * 64 + l) * 4;
        *(float4*)(mrow + idx) = *(float4*)&msk[idx];
    }
    out_probs[2 * n]     = c0 ? pp.x : 0.f;
    out_probs[2 * n + 1] = c1 ? pp.y : 0.f;
    out_idx[2 * n]       = (float)ii.x;
    out_idx[2 * n + 1]   = (float)ii.y;
    out_rank[2 * n]      = (float)rank0;
    out_rank[2 * n + 1]  = (float)rank1;
}

extern "C" void kernel_launch(void* const* d_in, const int* in_sizes, int n_in,
                              void* d_out, int out_size, void* d_ws, size_t ws_size,
                              hipStream_t stream) {
    const float* x = (const float*)d_in[0];
    const float* w = (const float*)d_in[1];
    const int N = in_sizes[0] / C_DIM;    // 32768
    const int G = N / 64;                 // 512

    int cap = (int)floor(2.0 * 2.0 * (double)N / 64.0);
    cap += cap & 1;
    if (cap < 4) cap = 4;

    char* wsb = (char*)d_ws;
    float*  w_t      = (float*)wsb;       wsb += (size_t)65536 * 4;
    int2*   idx_ws   = (int2*)wsb;        wsb += (size_t)N * 8;
    float2* probs_ws = (float2*)wsb;      wsb += (size_t)N * 8;
    int*    hist     = (int*)wsb;         wsb += (size_t)G * 128 * 4;
    int*    offs     = (int*)wsb;         wsb += (size_t)G * 128 * 4;
    int*    tot      = (int*)wsb;

    float* out       = (float*)d_out;
    float* out_mask  = out;                          // N*2*64
    float* out_probs = out + (size_t)N * 128;        // N*2
    float* out_idx   = out_probs + (size_t)N * 2;    // N*2
    float* out_rank  = out_idx + (size_t)N * 2;      // N*2

    hipLaunchKernelGGL(wt_kernel, dim3(256), dim3(256), 0, stream, w, w_t);
    hipLaunchKernelGGL(router_main, dim3(G), dim3(512), 0, stream,
                       x, w_t, idx_ws, probs_ws, hist);
    hipLaunchKernelGGL(scan_kernel, dim3(128), dim3(256), 0, stream,
                       hist, offs, tot, G);
    hipLaunchKernelGGL(rank_out, dim3(G), dim3(64), 0, stream,
                       idx_ws, probs_ws, offs, tot,
                       out_mask, out_probs, out_idx, out_rank, cap);
}

// Round 3
// 231.553 us; speedup vs baseline: 1.1678x; 1.1444x over previous
//
#include <hip/hip_runtime.h>
#include <math.h>

// Router: logits = x @ w^T (N=32768, C=1024, E=64), top-2 + softmax, stable
// k-major position-in-expert, capacity mask.
//
// K1 wprep: pack w into MFMA B-fragment layout as fp16 split pairs (hi, mid*2048)
// K2 router_main: 32x32x16 f16 MFMA, A-frags loaded direct from global fp32 and
//     split in-register; no LDS in K-loop. 8 waves/block (K split by 2, LDS
//     combine). Epilogue: top-2, softmax, per-group histograms.
// K3 scan_kernel: column-wise exclusive scan of group histograms
// K4 rank_out: ballot match-any stable rank + all outputs

#define C_DIM 1024

typedef _Float16 f16x8 __attribute__((ext_vector_type(8)));
typedef float f32x16 __attribute__((ext_vector_type(16)));

// w_frag elem index: ((f*64 + s)*64 + lane)*8 + j, f = split*2 + t
// content: n = t*32 + (lane&31), k = s*16 + (lane>>5)*8 + j
__global__ __launch_bounds__(256) void wprep(const float* __restrict__ w,
                                             _Float16* __restrict__ wf) {
    int id = blockIdx.x * 256 + threadIdx.x;    // 16384 threads
    int f = id >> 12;
    int s = (id >> 6) & 63;
    int lane = id & 63;
    int t = f & 1, split = f >> 1;
    int n = t * 32 + (lane & 31);
    int k = s * 16 + (lane >> 5) * 8;
    const float* src = w + (size_t)n * C_DIM + k;
    f16x8 v;
    #pragma unroll
    for (int j = 0; j < 8; ++j) {
        float xv = src[j];
        _Float16 h = (_Float16)xv;
        v[j] = (split == 0) ? h : (_Float16)((xv - (float)h) * 2048.0f);
    }
    *(f16x8*)(wf + (size_t)id * 8) = v;
}

__global__ __launch_bounds__(512) void router_main(
    const float* __restrict__ x, const _Float16* __restrict__ wf,
    int2* __restrict__ idx_ws, float2* __restrict__ probs_ws,
    int* __restrict__ hist)
{
    __shared__ float part[128 * 68];   // logits, stride 68 (bank-friendly)
    __shared__ int   h2[256];          // 2 groups x [k][expert]

    const int tid   = threadIdx.x;
    const int lane  = tid & 63;
    const int wv    = __builtin_amdgcn_readfirstlane(tid >> 6);  // 0..7
    const int mw    = wv & 3;        // m-tile within block
    const int kh    = wv >> 2;       // K half
    const int b     = blockIdx.x;
    const int m0    = b * 128 + mw * 32;
    const int lrow  = lane & 31;
    const int lhalf = lane >> 5;

    const float* xp = x + (size_t)(m0 + lrow) * C_DIM + kh * 512 + lhalf * 8;
    const _Float16* wp = wf + (size_t)lane * 8 + (size_t)(kh * 32) * 512;

    f32x16 ah0, ah1, as0, as1;
    #pragma unroll
    for (int i = 0; i < 16; ++i) { ah0[i] = 0.f; ah1[i] = 0.f; as0[i] = 0.f; as1[i] = 0.f; }

    #pragma unroll 4
    for (int s = 0; s < 32; ++s) {
        float4 a0 = *(const float4*)(xp + s * 16);
        float4 a1 = *(const float4*)(xp + s * 16 + 4);
        float av[8] = {a0.x, a0.y, a0.z, a0.w, a1.x, a1.y, a1.z, a1.w};
        f16x8 xh, xm;
        #pragma unroll
        for (int j = 0; j < 8; ++j) {
            _Float16 h = (_Float16)av[j];
            xh[j] = h;
            xm[j] = (_Float16)((av[j] - (float)h) * 2048.0f);
        }
        const _Float16* wps = wp + (size_t)s * 512;
        f16x8 bh0 = *(const f16x8*)(wps);
        f16x8 bh1 = *(const f16x8*)(wps + 32768);
        f16x8 bm0 = *(const f16x8*)(wps + 65536);
        f16x8 bm1 = *(const f16x8*)(wps + 98304);
        ah0 = __builtin_amdgcn_mfma_f32_32x32x16_f16(xh, bh0, ah0, 0, 0, 0);
        ah1 = __builtin_amdgcn_mfma_f32_32x32x16_f16(xh, bh1, ah1, 0, 0, 0);
        as0 = __builtin_amdgcn_mfma_f32_32x32x16_f16(xh, bm0, as0, 0, 0, 0);
        as0 = __builtin_amdgcn_mfma_f32_32x32x16_f16(xm, bh0, as0, 0, 0, 0);
        as1 = __builtin_amdgcn_mfma_f32_32x32x16_f16(xh, bm1, as1, 0, 0, 0);
        as1 = __builtin_amdgcn_mfma_f32_32x32x16_f16(xm, bh1, as1, 0, 0, 0);
    }

    const float inv = 1.0f / 2048.0f;
    if (kh == 1) {
        #pragma unroll
        for (int reg = 0; reg < 16; ++reg) {
            int r   = (reg & 3) + 8 * (reg >> 2) + 4 * lhalf;
            int tok = mw * 32 + r;
            part[tok * 68 + lrow]      = ah0[reg] + as0[reg] * inv;
            part[tok * 68 + 32 + lrow] = ah1[reg] + as1[reg] * inv;
        }
    }
    __syncthreads();
    if (kh == 0) {
        #pragma unroll
        for (int reg = 0; reg < 16; ++reg) {
            int r   = (reg & 3) + 8 * (reg >> 2) + 4 * lhalf;
            int tok = mw * 32 + r;
            part[tok * 68 + lrow]      += ah0[reg] + as0[reg] * inv;
            part[tok * 68 + 32 + lrow] += ah1[reg] + as1[reg] * inv;
        }
    } else {
        h2[tid - 256] = 0;
    }
    __syncthreads();

    if (tid < 128) {
        float m1 = -3.0e38f, m2 = -3.0e38f;
        int   i1 = 0, i2 = 0;
        const float* row = part + tid * 68;
        for (int e = 0; e < 64; ++e) {
            float v = row[e];
            if (v > m1)      { m2 = m1; i2 = i1; m1 = v; i1 = e; }
            else if (v > m2) { m2 = v;  i2 = e; }
        }
        float e2 = expf(m2 - m1);
        float p1 = 1.f / (1.f + e2);
        int n = b * 128 + tid;
        probs_ws[n] = make_float2(p1, e2 * p1);
        idx_ws[n]   = make_int2(i1, i2);
        int grp = tid >> 6;
        atomicAdd(&h2[grp * 128 + i1], 1);
        atomicAdd(&h2[grp * 128 + 64 + i2], 1);
    }
    __syncthreads();
    if (tid < 256) hist[b * 256 + tid] = h2[tid];
}

// exclusive prefix over groups for each of the 128 (k,expert) columns
__global__ __launch_bounds__(256) void scan_kernel(const int* __restrict__ hist,
                                                   int* __restrict__ offs,
                                                   int* __restrict__ tot, int G) {
    int c = blockIdx.x;          // 0..127
    int t = threadIdx.x;
    int ipt = G / 256;
    int base = t * ipt;
    int sum = 0;
    for (int j = 0; j < ipt; ++j) sum += hist[(size_t)(base + j) * 128 + c];
    int lane = t & 63, wvi = t >> 6;
    int sc = sum;
    #pragma unroll
    for (int d = 1; d < 64; d <<= 1) {
        int o = __shfl_up(sc, d, 64);
        if (lane >= d) sc += o;
    }
    __shared__ int wtot[4];
    if (lane == 63) wtot[wvi] = sc;
    __syncthreads();
    int pre = 0;
    for (int w2 = 0; w2 < wvi; ++w2) pre += wtot[w2];
    int run = pre + sc - sum;
    for (int j = 0; j < ipt; ++j) {
        int v = hist[(size_t)(base + j) * 128 + c];
        offs[(size_t)(base + j) * 128 + c] = run;
        run += v;
    }
    if (t == 255) tot[c] = run;
}

__global__ __launch_bounds__(64) void rank_out(
    const int2* __restrict__ idx_ws, const float2* __restrict__ probs_ws,
    const int* __restrict__ offs, const int* __restrict__ tot,
    float* __restrict__ out_mask, float* __restrict__ out_probs,
    float* __restrict__ out_idx,  float* __restrict__ out_rank, int cap)
{
    __shared__ float msk[64 * 128];
    const int g = blockIdx.x, l = threadIdx.x;
    const int n = g * 64 + l;

    #pragma unroll
    for (int j = 0; j < 32; ++j)
        *(float4*)&msk[(j * 64 + l) * 4] = make_float4(0.f, 0.f, 0.f, 0.f);

    int2   ii = idx_ws[n];
    float2 pp = probs_ws[n];
    int off0 = offs[g * 128 + ii.x];
    int off1 = offs[g * 128 + 64 + ii.y] + tot[ii.y];

    unsigned long long below = (1ull << l) - 1ull;
    unsigned long long m0 = ~0ull, m1 = ~0ull;
    #pragma unroll
    for (int bi = 0; bi < 6; ++bi) {
        unsigned long long b0 = __ballot((ii.x >> bi) & 1);
        unsigned long long b1 = __ballot((ii.y >> bi) & 1);
        m0 &= ((ii.x >> bi) & 1) ? b0 : ~b0;
        m1 &= ((ii.y >> bi) & 1) ? b1 : ~b1;
    }
    int rank0 = off0 + __popcll(m0 & below);
    int rank1 = off1 + __popcll(m1 & below);
    int c0 = rank0 < cap;
    int c1 = rank1 < cap;

    __syncthreads();
    if (c0) msk[l * 128 + ii.x] = 1.f;
    if (c1) msk[l * 128 + 64 + ii.y] = 1.f;
    __syncthreads();

    float* mrow = out_mask + (size_t)g * 8192;
    #pragma unroll
    for (int j = 0; j < 32; ++j) {
        int idx = (j * 64 + l) * 4;
        *(float4*)(mrow + idx) = *(float4*)&msk[idx];
    }
    out_probs[2 * n]     = c0 ? pp.x : 0.f;
    out_probs[2 * n + 1] = c1 ? pp.y : 0.f;
    out_idx[2 * n]       = (float)ii.x;
    out_idx[2 * n + 1]   = (float)ii.y;
    out_rank[2 * n]      = (float)rank0;
    out_rank[2 * n + 1]  = (float)rank1;
}

extern "C" void kernel_launch(void* const* d_in, const int* in_sizes, int n_in,
                              void* d_out, int out_size, void* d_ws, size_t ws_size,
                              hipStream_t stream) {
    const float* x = (const float*)d_in[0];
    const float* w = (const float*)d_in[1];
    const int N = in_sizes[0] / C_DIM;    // 32768
    const int G = N / 64;                 // 512

    int cap = (int)floor(2.0 * 2.0 * (double)N / 64.0);
    cap += cap & 1;
    if (cap < 4) cap = 4;

    char* wsb = (char*)d_ws;
    _Float16* wfrag  = (_Float16*)wsb;    wsb += (size_t)131072 * 2;
    int2*   idx_ws   = (int2*)wsb;        wsb += (size_t)N * 8;
    float2* probs_ws = (float2*)wsb;      wsb += (size_t)N * 8;
    int*    hist     = (int*)wsb;         wsb += (size_t)G * 128 * 4;
    int*    offs     = (int*)wsb;         wsb += (size_t)G * 128 * 4;
    int*    tot      = (int*)wsb;

    float* out       = (float*)d_out;
    float* out_mask  = out;                          // N*2*64
    float* out_probs = out + (size_t)N * 128;        // N*2
    float* out_idx   = out_probs + (size_t)N * 2;    // N*2
    float* out_rank  = out_idx + (size_t)N * 2;      // N*2

    hipLaunchKernelGGL(wprep, dim3(64), dim3(256), 0, stream, w, wfrag);
    hipLaunchKernelGGL(router_main, dim3(N / 128), dim3(512), 0, stream,
                       x, wfrag, idx_ws, probs_ws, hist);
    hipLaunchKernelGGL(scan_kernel, dim3(128), dim3(256), 0, stream,
                       hist, offs, tot, G);
    hipLaunchKernelGGL(rank_out, dim3(G), dim3(64), 0, stream,
                       idx_ws, probs_ws, offs, tot,
                       out_mask, out_probs, out_idx, out_rank, cap);
}

// Round 4
// 227.067 us; speedup vs baseline: 1.1909x; 1.0198x over previous
//
#include <hip/hip_runtime.h>
#include <math.h>

// Router: logits = x @ w^T (N=32768, C=1024, E=64), top-2 + softmax, stable
// k-major position-in-expert, capacity mask.
//
// K1 wprep: pack w into MFMA B-fragment fp16 split pairs (hi, mid*2048); also
//     zeroes the global histogram.
// K2 router_main: 32 tokens/block, K split 4-ways across the block's 4 waves.
//     32x32x16 f16 MFMA, A-frags straight from global fp32 (no LDS in K-loop).
//     grid=1024 -> 4 blocks/CU, 16 waves/CU for latency hiding. LDS combine,
//     top-2, LDS histogram -> global atomicAdd.
// K3 scan_kernel: column-wise exclusive scan of group histograms
// K4 rank_out: ballot match-any stable rank + all outputs

#define C_DIM 1024

typedef _Float16 f16x8 __attribute__((ext_vector_type(8)));
typedef float f32x16 __attribute__((ext_vector_type(16)));

// w_frag elem index: ((f*64 + s)*64 + lane)*8 + j, f = split*2 + t
// content: n = t*32 + (lane&31), k = s*16 + (lane>>5)*8 + j
__global__ __launch_bounds__(256) void wprep(const float* __restrict__ w,
                                             _Float16* __restrict__ wf,
                                             int* __restrict__ hist, int histN) {
    int id = blockIdx.x * 256 + threadIdx.x;    // 16384 threads
    if (id * 4 < histN)
        *(int4*)(hist + id * 4) = make_int4(0, 0, 0, 0);
    int f = id >> 12;
    int s = (id >> 6) & 63;
    int lane = id & 63;
    int t = f & 1, split = f >> 1;
    int n = t * 32 + (lane & 31);
    int k = s * 16 + (lane >> 5) * 8;
    const float* src = w + (size_t)n * C_DIM + k;
    f16x8 v;
    #pragma unroll
    for (int j = 0; j < 8; ++j) {
        float xv = src[j];
        _Float16 h = (_Float16)xv;
        v[j] = (split == 0) ? h : (_Float16)((xv - (float)h) * 2048.0f);
    }
    *(f16x8*)(wf + (size_t)id * 8) = v;
}

__global__ __launch_bounds__(256, 4) void router_main(
    const float* __restrict__ x, const _Float16* __restrict__ wf,
    int2* __restrict__ idx_ws, float2* __restrict__ probs_ws,
    int* __restrict__ hist)
{
    __shared__ float part[32 * 68];
    __shared__ int   h2[128];

    const int tid   = threadIdx.x;
    const int lane  = tid & 63;
    const int kh    = __builtin_amdgcn_readfirstlane(tid >> 6);  // K quarter 0..3
    const int b     = blockIdx.x;                                // 0..1023
    const int m0    = b * 32;
    const int lrow  = lane & 31;
    const int lhalf = lane >> 5;

    const float* xp = x + (size_t)(m0 + lrow) * C_DIM + kh * 256 + lhalf * 8;
    const _Float16* wp = wf + (size_t)lane * 8 + (size_t)(kh * 16) * 512;

    f32x16 ah0, ah1, as0, as1;
    #pragma unroll
    for (int i = 0; i < 16; ++i) { ah0[i] = 0.f; ah1[i] = 0.f; as0[i] = 0.f; as1[i] = 0.f; }

    #pragma unroll 4
    for (int s = 0; s < 16; ++s) {
        float4 a0 = *(const float4*)(xp + s * 16);
        float4 a1 = *(const float4*)(xp + s * 16 + 4);
        float av[8] = {a0.x, a0.y, a0.z, a0.w, a1.x, a1.y, a1.z, a1.w};
        f16x8 xh, xm;
        #pragma unroll
        for (int j = 0; j < 8; ++j) {
            _Float16 h = (_Float16)av[j];
            xh[j] = h;
            xm[j] = (_Float16)((av[j] - (float)h) * 2048.0f);
        }
        const _Float16* wps = wp + (size_t)s * 512;
        f16x8 bh0 = *(const f16x8*)(wps);
        f16x8 bh1 = *(const f16x8*)(wps + 32768);
        f16x8 bm0 = *(const f16x8*)(wps + 65536);
        f16x8 bm1 = *(const f16x8*)(wps + 98304);
        ah0 = __builtin_amdgcn_mfma_f32_32x32x16_f16(xh, bh0, ah0, 0, 0, 0);
        ah1 = __builtin_amdgcn_mfma_f32_32x32x16_f16(xh, bh1, ah1, 0, 0, 0);
        as0 = __builtin_amdgcn_mfma_f32_32x32x16_f16(xh, bm0, as0, 0, 0, 0);
        as0 = __builtin_amdgcn_mfma_f32_32x32x16_f16(xm, bh0, as0, 0, 0, 0);
        as1 = __builtin_amdgcn_mfma_f32_32x32x16_f16(xh, bm1, as1, 0, 0, 0);
        as1 = __builtin_amdgcn_mfma_f32_32x32x16_f16(xm, bh1, as1, 0, 0, 0);
    }

    if (tid < 128) h2[tid] = 0;
    const float inv = 1.0f / 2048.0f;
    #pragma unroll 1
    for (int r = 0; r < 4; ++r) {
        if (kh == r) {
            #pragma unroll
            for (int reg = 0; reg < 16; ++reg) {
                int row = (reg & 3) + 8 * (reg >> 2) + 4 * lhalf;
                float v0 = ah0[reg] + as0[reg] * inv;
                float v1 = ah1[reg] + as1[reg] * inv;
                if (r == 0) {
                    part[row * 68 + lrow]      = v0;
                    part[row * 68 + 32 + lrow] = v1;
                } else {
                    part[row * 68 + lrow]      += v0;
                    part[row * 68 + 32 + lrow] += v1;
                }
            }
        }
        __syncthreads();
    }

    if (tid < 32) {
        float m1 = -3.0e38f, m2 = -3.0e38f;
        int   i1 = 0, i2 = 0;
        const float* row = part + tid * 68;
        for (int e = 0; e < 64; ++e) {
            float v = row[e];
            if (v > m1)      { m2 = m1; i2 = i1; m1 = v; i1 = e; }
            else if (v > m2) { m2 = v;  i2 = e; }
        }
        float e2 = expf(m2 - m1);
        float p1 = 1.f / (1.f + e2);
        int n = m0 + tid;
        probs_ws[n] = make_float2(p1, e2 * p1);
        idx_ws[n]   = make_int2(i1, i2);
        atomicAdd(&h2[i1], 1);
        atomicAdd(&h2[64 + i2], 1);
    }
    __syncthreads();
    if (tid < 128) {
        int v = h2[tid];
        if (v) atomicAdd(&hist[(b >> 1) * 128 + tid], v);
    }
}

// exclusive prefix over groups for each of the 128 (k,expert) columns
__global__ __launch_bounds__(256) void scan_kernel(const int* __restrict__ hist,
                                                   int* __restrict__ offs,
                                                   int* __restrict__ tot, int G) {
    int c = blockIdx.x;          // 0..127
    int t = threadIdx.x;
    int ipt = G / 256;
    int base = t * ipt;
    int sum = 0;
    for (int j = 0; j < ipt; ++j) sum += hist[(size_t)(base + j) * 128 + c];
    int lane = t & 63, wvi = t >> 6;
    int sc = sum;
    #pragma unroll
    for (int d = 1; d < 64; d <<= 1) {
        int o = __shfl_up(sc, d, 64);
        if (lane >= d) sc += o;
    }
    __shared__ int wtot[4];
    if (lane == 63) wtot[wvi] = sc;
    __syncthreads();
    int pre = 0;
    for (int w2 = 0; w2 < wvi; ++w2) pre += wtot[w2];
    int run = pre + sc - sum;
    for (int j = 0; j < ipt; ++j) {
        int v = hist[(size_t)(base + j) * 128 + c];
        offs[(size_t)(base + j) * 128 + c] = run;
        run += v;
    }
    if (t == 255) tot[c] = run;
}

__global__ __launch_bounds__(64) void rank_out(
    const int2* __restrict__ idx_ws, const float2* __restrict__ probs_ws,
    const int* __restrict__ offs, const int* __restrict__ tot,
    float* __restrict__ out_mask, float* __restrict__ out_probs,
    float* __restrict__ out_idx,  float* __restrict__ out_rank, int cap)
{
    __shared__ float msk[64 * 128];
    const int g = blockIdx.x, l = threadIdx.x;
    const int n = g * 64 + l;

    #pragma unroll
    for (int j = 0; j < 32; ++j)
        *(float4*)&msk[(j * 64 + l) * 4] = make_float4(0.f, 0.f, 0.f, 0.f);

    int2   ii = idx_ws[n];
    float2 pp = probs_ws[n];
    int off0 = offs[g * 128 + ii.x];
    int off1 = offs[g * 128 + 64 + ii.y] + tot[ii.y];

    unsigned long long below = (1ull << l) - 1ull;
    unsigned long long m0 = ~0ull, m1 = ~0ull;
    #pragma unroll
    for (int bi = 0; bi < 6; ++bi) {
        unsigned long long b0 = __ballot((ii.x >> bi) & 1);
        unsigned long long b1 = __ballot((ii.y >> bi) & 1);
        m0 &= ((ii.x >> bi) & 1) ? b0 : ~b0;
        m1 &= ((ii.y >> bi) & 1) ? b1 : ~b1;
    }
    int rank0 = off0 + __popcll(m0 & below);
    int rank1 = off1 + __popcll(m1 & below);
    int c0 = rank0 < cap;
    int c1 = rank1 < cap;

    __syncthreads();
    if (c0) msk[l * 128 + ii.x] = 1.f;
    if (c1) msk[l * 128 + 64 + ii.y] = 1.f;
    __syncthreads();

    float* mrow = out_mask + (size_t)g * 8192;
    #pragma unroll
    for (int j = 0; j < 32; ++j) {
        int idx = (j * 64 + l) * 4;
        *(float4*)(mrow + idx) = *(float4*)&msk[idx];
    }
    out_probs[2 * n]     = c0 ? pp.x : 0.f;
    out_probs[2 * n + 1] = c1 ? pp.y : 0.f;
    out_idx[2 * n]       = (float)ii.x;
    out_idx[2 * n + 1]   = (float)ii.y;
    out_rank[2 * n]      = (float)rank0;
    out_rank[2 * n + 1]  = (float)rank1;
}

extern "C" void kernel_launch(void* const* d_in, const int* in_sizes, int n_in,
                              void* d_out, int out_size, void* d_ws, size_t ws_size,
                              hipStream_t stream) {
    const float* x = (const float*)d_in[0];
    const float* w = (const float*)d_in[1];
    const int N = in_sizes[0] / C_DIM;    // 32768
    const int G = N / 64;                 // 512

    int cap = (int)floor(2.0 * 2.0 * (double)N / 64.0);
    cap += cap & 1;
    if (cap < 4) cap = 4;

    char* wsb = (char*)d_ws;
    _Float16* wfrag  = (_Float16*)wsb;    wsb += (size_t)131072 * 2;
    int2*   idx_ws   = (int2*)wsb;        wsb += (size_t)N * 8;
    float2* probs_ws = (float2*)wsb;      wsb += (size_t)N * 8;
    int*    hist     = (int*)wsb;         wsb += (size_t)G * 128 * 4;
    int*    offs     = (int*)wsb;         wsb += (size_t)G * 128 * 4;
    int*    tot      = (int*)wsb;

    float* out       = (float*)d_out;
    float* out_mask  = out;                          // N*2*64
    float* out_probs = out + (size_t)N * 128;        // N*2
    float* out_idx   = out_probs + (size_t)N * 2;    // N*2
    float* out_rank  = out_idx + (size_t)N * 2;      // N*2

    hipLaunchKernelGGL(wprep, dim3(64), dim3(256), 0, stream, w, wfrag,
                       hist, G * 128);
    hipLaunchKernelGGL(router_main, dim3(N / 32), dim3(256), 0, stream,
                       x, wfrag, idx_ws, probs_ws, hist);
    hipLaunchKernelGGL(scan_kernel, dim3(128), dim3(256), 0, stream,
                       hist, offs, tot, G);
    hipLaunchKernelGGL(rank_out, dim3(G), dim3(64), 0, stream,
                       idx_ws, probs_ws, offs, tot,
                       out_mask, out_probs, out_idx, out_rank, cap);
}

// Round 5
// 224.906 us; speedup vs baseline: 1.2023x; 1.0096x over previous
//
#include <hip/hip_runtime.h>
#include <math.h>

// Router: logits = x @ w^T (N=32768, C=1024, E=64), top-2 + softmax, stable
// k-major position-in-expert, capacity mask.
//
// K1 wprep: pack w into MFMA B-frag fp16 split pairs (hi, mid*2048)
// K2 router_main: 64 tok x 64 exp per block, 4 waves = (tok-half x exp-half),
//     full K per wave. x staged global_load_lds (async DMA, width=16) into a
//     32KB XOR-swizzled LDS tile; ds_read_b128 conflict-free; 32x32x16 f16
//     MFMA split arithmetic. Epilogue: top-2, softmax, per-group histogram.
// K3 scan_kernel: column-wise exclusive scan of group histograms
// K4 rank_out: ballot match-any stable rank + coalesced outputs (256 thr)

#define C_DIM 1024
#define BK 128

typedef _Float16 f16x8 __attribute__((ext_vector_type(8)));
typedef float f32x16 __attribute__((ext_vector_type(16)));

// wf frag id = (s*4 + eh*2 + split)*512 + lane*8 (f16 units)
// content: n = eh*32 + (lane&31) (expert), k = s*16 + (lane>>5)*8 + j
__global__ __launch_bounds__(256) void wprep(const float* __restrict__ w,
                                             _Float16* __restrict__ wf) {
    int id = blockIdx.x * 256 + threadIdx.x;   // 16384 frags-of-8
    int lane = id & 63;
    int q = id >> 6;            // 0..255
    int split = q & 1;
    int eh = (q >> 1) & 1;
    int s = q >> 2;             // 0..63
    int n = eh * 32 + (lane & 31);
    int k = s * 16 + (lane >> 5) * 8;
    const float* src = w + (size_t)n * C_DIM + k;
    f16x8 v;
    #pragma unroll
    for (int j = 0; j < 8; ++j) {
        float xv = src[j];
        _Float16 h = (_Float16)xv;
        v[j] = (split == 0) ? h : (_Float16)((xv - (float)h) * 2048.0f);
    }
    *(f16x8*)(wf + (size_t)id * 8) = v;
}

__global__ __launch_bounds__(256, 4) void router_main(
    const float* __restrict__ x, const _Float16* __restrict__ wf,
    int2* __restrict__ idx_ws, float2* __restrict__ probs_ws,
    int* __restrict__ hist)
{
    // xs: 64 rows x 128 floats = 32 KB. 16B chunk (m, c) stored at physical
    // chunk (m, (c&16)|((c^(m&15))&15)) -> ds_read_b128 conflict-free AND
    // staging stays lane-contiguous (global_load_lds requirement).
    __shared__ __align__(16) float xs[64 * BK];
    __shared__ int h2[128];

    const int tid  = threadIdx.x;
    const int lane = tid & 63;
    const int wv   = __builtin_amdgcn_readfirstlane(tid >> 6);
    const int th   = wv >> 1;      // token half
    const int eh   = wv & 1;       // expert half
    const int b    = blockIdx.x;
    const int m0   = b * 64;

    // staging: 2048 16B chunks / 4 waves / 64 lanes = 8 instrs per thread
    uint32_t goff[8];
    const int p0 = wv * 512 + lane;
    #pragma unroll
    for (int i = 0; i < 8; ++i) {
        int p = p0 + i * 64;          // physical chunk index
        int m = p >> 5;               // row 0..63
        int rem = p & 31;             // physical chunk-in-row
        int c = (rem & 16) | ((rem ^ (m & 15)) & 15);   // logical chunk
        goff[i] = (uint32_t)(m0 + m) * C_DIM + c * 4;   // float offset (+ck)
    }

    const int mm   = lane & 15;
    const int lh   = lane >> 5;
    const int mloc = th * 32 + (lane & 31);

    f32x16 ah, am;
    #pragma unroll
    for (int i = 0; i < 16; ++i) { ah[i] = 0.f; am[i] = 0.f; }

    const _Float16* wbase = wf + (size_t)eh * 1024 + (size_t)lane * 8;

    for (int ch = 0; ch < 8; ++ch) {
        __syncthreads();   // WAR on xs
        #pragma unroll
        for (int i = 0; i < 8; ++i) {
            __builtin_amdgcn_global_load_lds(
                (const __attribute__((address_space(1))) uint32_t*)(x + goff[i] + ch * BK),
                (__attribute__((address_space(3))) uint32_t*)(xs + (size_t)(wv * 512 + i * 64) * 4),
                16, 0, 0);
        }
        __syncthreads();   // drains vmcnt
        #pragma unroll
        for (int s8 = 0; s8 < 8; ++s8) {
            const int s  = ch * 8 + s8;
            const int c0 = s8 * 4 + lh * 2;
            const int c1 = c0 + 1;
            const int pc0 = (c0 & 16) | ((c0 ^ mm) & 15);
            const int pc1 = (c1 & 16) | ((c1 ^ mm) & 15);
            float4 a0 = *(const float4*)&xs[(size_t)(mloc * 32 + pc0) * 4];
            float4 a1 = *(const float4*)&xs[(size_t)(mloc * 32 + pc1) * 4];
            float av[8] = {a0.x, a0.y, a0.z, a0.w, a1.x, a1.y, a1.z, a1.w};
            f16x8 xh, xm;
            #pragma unroll
            for (int j = 0; j < 8; ++j) {
                _Float16 hh = (_Float16)av[j];
                xh[j] = hh;
                xm[j] = (_Float16)((av[j] - (float)hh) * 2048.0f);
            }
            const _Float16* wp = wbase + (size_t)s * 2048;
            f16x8 bh = *(const f16x8*)(wp);
            f16x8 bm = *(const f16x8*)(wp + 512);
            ah = __builtin_amdgcn_mfma_f32_32x32x16_f16(xh, bh, ah, 0, 0, 0);
            am = __builtin_amdgcn_mfma_f32_32x32x16_f16(xh, bm, am, 0, 0, 0);
            am = __builtin_amdgcn_mfma_f32_32x32x16_f16(xm, bh, am, 0, 0, 0);
        }
    }
    __syncthreads();   // xs dead; alias as part[64][69]

    {
        const float inv = 1.0f / 2048.0f;
        const int col = lane & 31;
        #pragma unroll
        for (int reg = 0; reg < 16; ++reg) {
            int row = (reg & 3) + 8 * (reg >> 2) + 4 * lh;
            xs[(size_t)(th * 32 + row) * 69 + eh * 32 + col] = ah[reg] + am[reg] * inv;
        }
    }
    if (tid < 128) h2[tid] = 0;
    __syncthreads();

    if (tid < 64) {
        float m1 = -3.0e38f, m2 = -3.0e38f;
        int   i1 = 0, i2 = 0;
        const float* row = xs + (size_t)tid * 69;
        for (int e = 0; e < 64; ++e) {
            float v = row[e];
            if (v > m1)      { m2 = m1; i2 = i1; m1 = v; i1 = e; }
            else if (v > m2) { m2 = v;  i2 = e; }
        }
        float e2 = expf(m2 - m1);
        float p1 = 1.f / (1.f + e2);
        int n = m0 + tid;
        probs_ws[n] = make_float2(p1, e2 * p1);
        idx_ws[n]   = make_int2(i1, i2);
        atomicAdd(&h2[i1], 1);
        atomicAdd(&h2[64 + i2], 1);
    }
    __syncthreads();
    if (tid < 128) hist[(size_t)b * 128 + tid] = h2[tid];
}

// exclusive prefix over groups for each of the 128 (k,expert) columns
__global__ __launch_bounds__(256) void scan_kernel(const int* __restrict__ hist,
                                                   int* __restrict__ offs,
                                                   int* __restrict__ tot, int G) {
    int c = blockIdx.x;          // 0..127
    int t = threadIdx.x;
    int ipt = G / 256;
    int base = t * ipt;
    int sum = 0;
    for (int j = 0; j < ipt; ++j) sum += hist[(size_t)(base + j) * 128 + c];
    int lane = t & 63, wvi = t >> 6;
    int sc = sum;
    #pragma unroll
    for (int d = 1; d < 64; d <<= 1) {
        int o = __shfl_up(sc, d, 64);
        if (lane >= d) sc += o;
    }
    __shared__ int wtot[4];
    if (lane == 63) wtot[wvi] = sc;
    __syncthreads();
    int pre = 0;
    for (int w2 = 0; w2 < wvi; ++w2) pre += wtot[w2];
    int run = pre + sc - sum;
    for (int j = 0; j < ipt; ++j) {
        int v = hist[(size_t)(base + j) * 128 + c];
        offs[(size_t)(base + j) * 128 + c] = run;
        run += v;
    }
    if (t == 255) tot[c] = run;
}

__global__ __launch_bounds__(256) void rank_out(
    const int2* __restrict__ idx_ws, const float2* __restrict__ probs_ws,
    const int* __restrict__ offs, const int* __restrict__ tot,
    float* __restrict__ out_mask, float* __restrict__ out_probs,
    float* __restrict__ out_idx,  float* __restrict__ out_rank, int cap)
{
    __shared__ float msk[64 * 128];   // 32 KB
    const int g = blockIdx.x, t = threadIdx.x;

    #pragma unroll
    for (int j = 0; j < 8; ++j)
        *(float4*)&msk[(size_t)(j * 256 + t) * 4] = make_float4(0.f, 0.f, 0.f, 0.f);
    __syncthreads();

    if (t < 64) {
        const int l = t;
        const int n = g * 64 + l;
        int2   ii = idx_ws[n];
        float2 pp = probs_ws[n];
        int off0 = offs[g * 128 + ii.x];
        int off1 = offs[g * 128 + 64 + ii.y] + tot[ii.y];

        unsigned long long below = (1ull << l) - 1ull;
        unsigned long long mk0 = ~0ull, mk1 = ~0ull;
        #pragma unroll
        for (int bi = 0; bi < 6; ++bi) {
            unsigned long long b0 = __ballot((ii.x >> bi) & 1);
            unsigned long long b1 = __ballot((ii.y >> bi) & 1);
            mk0 &= ((ii.x >> bi) & 1) ? b0 : ~b0;
            mk1 &= ((ii.y >> bi) & 1) ? b1 : ~b1;
        }
        int rank0 = off0 + __popcll(mk0 & below);
        int rank1 = off1 + __popcll(mk1 & below);
        int c0 = rank0 < cap;
        int c1 = rank1 < cap;

        if (c0) msk[l * 128 + ii.x] = 1.f;
        if (c1) msk[l * 128 + 64 + ii.y] = 1.f;

        out_probs[2 * n]     = c0 ? pp.x : 0.f;
        out_probs[2 * n + 1] = c1 ? pp.y : 0.f;
        out_idx[2 * n]       = (float)ii.x;
        out_idx[2 * n + 1]   = (float)ii.y;
        out_rank[2 * n]      = (float)rank0;
        out_rank[2 * n + 1]  = (float)rank1;
    }
    __syncthreads();

    float* mrow = out_mask + (size_t)g * 8192;
    #pragma unroll
    for (int j = 0; j < 8; ++j) {
        size_t idx4 = (size_t)(j * 256 + t) * 4;
        *(float4*)(mrow + idx4) = *(float4*)&msk[idx4];
    }
}

extern "C" void kernel_launch(void* const* d_in, const int* in_sizes, int n_in,
                              void* d_out, int out_size, void* d_ws, size_t ws_size,
                              hipStream_t stream) {
    const float* x = (const float*)d_in[0];
    const float* w = (const float*)d_in[1];
    const int N = in_sizes[0] / C_DIM;    // 32768
    const int G = N / 64;                 // 512

    int cap = (int)floor(2.0 * 2.0 * (double)N / 64.0);
    cap += cap & 1;
    if (cap < 4) cap = 4;

    char* wsb = (char*)d_ws;
    _Float16* wfrag  = (_Float16*)wsb;    wsb += (size_t)131072 * 2;
    int2*   idx_ws   = (int2*)wsb;        wsb += (size_t)N * 8;
    float2* probs_ws = (float2*)wsb;      wsb += (size_t)N * 8;
    int*    hist     = (int*)wsb;         wsb += (size_t)G * 128 * 4;
    int*    offs     = (int*)wsb;         wsb += (size_t)G * 128 * 4;
    int*    tot      = (int*)wsb;

    float* out       = (float*)d_out;
    float* out_mask  = out;                          // N*2*64
    float* out_probs = out + (size_t)N * 128;        // N*2
    float* out_idx   = out_probs + (size_t)N * 2;    // N*2
    float* out_rank  = out_idx + (size_t)N * 2;      // N*2

    hipLaunchKernelGGL(wprep, dim3(64), dim3(256), 0, stream, w, wfrag);
    hipLaunchKernelGGL(router_main, dim3(G), dim3(256), 0, stream,
                       x, wfrag, idx_ws, probs_ws, hist);
    hipLaunchKernelGGL(scan_kernel, dim3(128), dim3(256), 0, stream,
                       hist, offs, tot, G);
    hipLaunchKernelGGL(rank_out, dim3(G), dim3(256), 0, stream,
                       idx_ws, probs_ws, offs, tot,
                       out_mask, out_probs, out_idx, out_rank, cap);
}